// Round 9
// baseline (264.829 us; speedup 1.0000x reference)
//
#include <hip/hip_runtime.h>
#include <math.h>

#define B_  8
#define R_  64
#define C_  256
#define NH_ 8
#define N_  4096
#define HD_ 32

__device__ __forceinline__ float softplus_rcp(float s) {
    return 1.f / __logf(1.f + __expf(s));     // 1/softplus, fast intrinsics
}

// async 16B global->LDS (no VGPR round-trip). Dest must be linear in lane:
// HW writes readfirstlane(base) + lane*16; our per-lane dest IS base+lane*16.
__device__ __forceinline__ void gload16_lds(const float* g, float* l) {
    __builtin_amdgcn_global_load_lds(
        (const __attribute__((address_space(1))) unsigned int*)g,
        (__attribute__((address_space(3))) unsigned int*)l, 16, 0, 0);
}

// ---------------------------------------------------------------------------
// ROLE KV (kernelA even blocks): k/v kv-aggregation, KV8 body verbatim.
// ---------------------------------------------------------------------------
static __device__ __forceinline__ void roleKV(
        const float* __restrict__ qkv, const float* __restrict__ pos,
        const float* __restrict__ scale, float* __restrict__ part,
        float* __restrict__ kspart, float* smem, int kvb, int t) {
    float* rsc_s = smem + 8192;
    const int wave = t >> 6, lane = t & 63;
    const int tk   = lane >> 5;
    const int lr   = lane & 31;
    const int tok0 = kvb * 32;
    const int row  = wave * 2 + tk;

    rsc_s[t] = softplus_rcp(scale[t]);

    const size_t qbase = (size_t)tok0 * C_;
    const size_t koff  = (size_t)B_ * N_ * C_;
    const size_t voff  = (size_t)2 * B_ * N_ * C_;

    const int h  = t >> 5;
    const int l  = t & 31;
    const int cg = l & 7;
    const int dg = l >> 3;

    float acc[4][8];
    #pragma unroll
    for (int ii = 0; ii < 4; ii++)
        #pragma unroll
        for (int jj = 0; jj < 8; jj++) acc[ii][jj] = 0.f;
    float ksp[4] = {0.f, 0.f, 0.f, 0.f};

    float4 sk[2], sp[2];
    float  rs[8];

    auto LOAD = [&](int tt) {
        float* vdst = smem + 4096 + (tt & 1) * 2048;
        const int r0 = wave * 2;
        const size_t vsrc = voff + qbase + (size_t)(tt * 8 + r0) * C_;
        gload16_lds(qkv + vsrc + lane * 4,      vdst + r0 * 256 + lane * 4);
        gload16_lds(qkv + vsrc + C_ + lane * 4, vdst + (r0 + 1) * 256 + lane * 4);
        const int    nrow = tt * 8 + row;
        const size_t off  = qbase + (size_t)nrow * C_;
        const size_t poff = (size_t)((tok0 + nrow) & (N_ - 1)) * C_;
        sk[0] = *(const float4*)(qkv + koff + off + lr * 4);
        sk[1] = *(const float4*)(qkv + koff + off + 128 + lr * 4);
        sp[0] = *(const float4*)(pos + poff + lr * 4);
        sp[1] = *(const float4*)(pos + poff + 128 + lr * 4);
    };

    auto PROC = [&](int tt) {
        float* kf_s = smem + (tt & 1) * 2048;
        float kc[8];
        float sk2 = 0.f, sk6 = 0.f;
        #pragma unroll
        for (int j = 0; j < 2; j++) {
            const float ka[4] = {sk[j].x, sk[j].y, sk[j].z, sk[j].w};
            const float pa[4] = {sp[j].x, sp[j].y, sp[j].z, sp[j].w};
            #pragma unroll
            for (int e = 0; e < 4; e++) {
                const float r  = rs[j * 4 + e];
                const float kw = (fmaxf(ka[e] + pa[e], 0.f) + 1e-6f) * r;
                sk2 += kw * kw;
                const float k3 = kw * kw * kw;
                sk6 += k3 * k3;
                kc[j * 4 + e] = k3;
            }
        }
        #pragma unroll
        for (int m = 1; m < 32; m <<= 1) {
            sk2 += __shfl_xor(sk2, m, 64);
            sk6 += __shfl_xor(sk6, m, 64);
        }
        const float ks = sqrtf(sk2) * rsqrtf(sk6);
        #pragma unroll
        for (int j = 0; j < 2; j++) {
            const float4 kf4 = make_float4(kc[j*4+0] * ks, kc[j*4+1] * ks,
                                           kc[j*4+2] * ks, kc[j*4+3] * ks);
            *(float4*)&kf_s[row * 256 + j * 128 + lr * 4] = kf4;
        }
    };

    auto COMP = [&](int tt) {
        const float* kf_s = smem + (tt & 1) * 2048;
        const float* v_s  = smem + 4096 + (tt & 1) * 2048;
        const float* kfp = kf_s + h * HD_ + cg * 4;
        const float* vp  = v_s  + h * HD_ + dg * 8;
        #pragma unroll
        for (int nl = 0; nl < 8; nl++) {
            const float4 kr = *(const float4*)(kfp + nl * 256);
            const float4 va = *(const float4*)(vp  + nl * 256);
            const float4 vb = *(const float4*)(vp  + nl * 256 + 4);
            ksp[0] += kr.x;  ksp[1] += kr.y;
            ksp[2] += kr.z;  ksp[3] += kr.w;
            const float kk[4] = {kr.x, kr.y, kr.z, kr.w};
            const float vv[8] = {va.x, va.y, va.z, va.w,
                                 vb.x, vb.y, vb.z, vb.w};
            #pragma unroll
            for (int ii = 0; ii < 4; ii++)
                #pragma unroll
                for (int jj = 0; jj < 8; jj++)
                    acc[ii][jj] = fmaf(kk[ii], vv[jj], acc[ii][jj]);
        }
    };

    LOAD(0);
    __syncthreads();
    #pragma unroll
    for (int j = 0; j < 2; j++)
        *(float4*)&rs[j * 4] = *(const float4*)&rsc_s[j * 128 + lr * 4];
    PROC(0);
    LOAD(1);
    __syncthreads();
    #pragma unroll
    for (int tt = 0; tt < 4; tt++) {
        COMP(tt);
        if (tt < 3) PROC(tt + 1);
        __syncthreads();
        if (tt < 2) LOAD(tt + 2);
    }

    #pragma unroll
    for (int ii = 0; ii < 4; ii++) {
        const float4 a = make_float4(acc[ii][0], acc[ii][1], acc[ii][2], acc[ii][3]);
        const float4 b = make_float4(acc[ii][4], acc[ii][5], acc[ii][6], acc[ii][7]);
        const int base = h * 1024 + (cg * 4 + ii) * 32 + dg * 8;
        *(float4*)&smem[base]     = a;
        *(float4*)&smem[base + 4] = b;
    }
    if (dg == 0)
        *(float4*)&kspart[(size_t)kvb * 256 + h * 32 + cg * 4] =
            make_float4(ksp[0], ksp[1], ksp[2], ksp[3]);
    __syncthreads();
    float* pdst = part + (size_t)kvb * 8192;
    #pragma unroll
    for (int i = 0; i < 8; i++)
        *(float4*)&pdst[i * 1024 + t * 4] = *(const float4*)&smem[i * 1024 + t * 4];
}

// ---------------------------------------------------------------------------
// ROLE CONV (kernelA odd blocks): CD2's halo + both depthwise convs; writes
// fm+lepe (conv-only result) straight to out. Attn added later by kernelC.
// ---------------------------------------------------------------------------
static __device__ __forceinline__ void roleCONV(
        const float* __restrict__ qkv,
        const float* __restrict__ w_v,  const float* __restrict__ b_v,
        const float* __restrict__ w_dwc, const float* __restrict__ b_dwc,
        float* __restrict__ out, float* v_s, int cb, int t) {
    const int tile = cb & 15;
    const int h    = (cb >> 4) & 7;
    const int b    = cb >> 7;
    const int ty0  = (tile >> 2) * 16, tx0 = (tile & 3) * 16;

    const float* vb = qkv + (size_t)2 * B_ * N_ * C_ + (size_t)b * N_ * C_ + h * HD_;
    #pragma unroll
    for (int i = 0; i < 13; i++) {
        const int idx = i * 256 + t;
        if (idx < 3200) {
            const int pix = idx >> 3, d4 = (idx & 7) * 4;
            const int yy = pix / 20, xx = pix - yy * 20;
            const int gy = ty0 + yy - 2, gx = tx0 + xx - 2;
            float4 val = make_float4(0.f, 0.f, 0.f, 0.f);
            if (gy >= 0 && gy < R_ && gx >= 0 && gx < R_)
                val = *(const float4*)(vb + (size_t)(gy * R_ + gx) * C_ + d4);
            *(float4*)&v_s[pix * 32 + d4] = val;
        }
    }

    const int c  = t & 31, pg = t >> 5;
    float wv[9], wd[25];
    {
        const float* wvp = w_v + (size_t)(h * HD_ + c) * 9;
        const float* wdp = w_dwc + (size_t)c * 25;
        #pragma unroll
        for (int i = 0; i < 9; i++)  wv[i] = wvp[i];
        #pragma unroll
        for (int i = 0; i < 25; i++) wd[i] = wdp[i];
    }
    const float bias = b_v[h * HD_ + c] + b_dwc[c];
    __syncthreads();

    float res[32];
    #pragma unroll
    for (int r2 = 0; r2 < 2; r2++) {
        const int ty = pg * 2 + r2;
        float win[5][5];
        #pragma unroll
        for (int j = 0; j < 5; j++)
            #pragma unroll
            for (int i = 0; i < 5; i++)
                win[j][i] = v_s[((ty + i) * 20 + j) * 32 + c];
        #pragma unroll
        for (int tx = 0; tx < 16; tx++) {
            float a = bias;
            #pragma unroll
            for (int j = 0; j < 5; j++) {
                const int slot = (tx + j) % 5;
                #pragma unroll
                for (int i = 0; i < 5; i++)
                    a = fmaf(wd[i * 5 + j], win[slot][i], a);
            }
            #pragma unroll
            for (int j = 1; j < 4; j++) {
                const int slot = (tx + j) % 5;
                #pragma unroll
                for (int i = 1; i < 4; i++)
                    a = fmaf(wv[(i - 1) * 3 + (j - 1)], win[slot][i], a);
            }
            res[r2 * 16 + tx] = a;
            if (tx < 15) {
                const int slot = tx % 5;
                #pragma unroll
                for (int i = 0; i < 5; i++)
                    win[slot][i] = v_s[((ty + i) * 20 + (tx + 5)) * 32 + c];
            }
        }
    }
    __syncthreads();
    #pragma unroll
    for (int r2 = 0; r2 < 2; r2++)
        #pragma unroll
        for (int tx = 0; tx < 16; tx++)
            v_s[((pg * 2 + r2) * 16 + tx) * 33 + c] = res[r2 * 16 + tx];
    __syncthreads();

    const int tyy = t >> 4, txx = t & 15;
    const int tok = b * N_ + (ty0 + tyy) * R_ + (tx0 + txx);
    float4* dst = (float4*)(out + (size_t)tok * C_ + h * HD_);
    #pragma unroll
    for (int i = 0; i < 8; i++) {
        float4 v4;
        v4.x = v_s[t * 33 + i*4+0];
        v4.y = v_s[t * 33 + i*4+1];
        v4.z = v_s[t * 33 + i*4+2];
        v4.w = v_s[t * 33 + i*4+3];
        dst[i] = v4;
    }
}

// ---------------------------------------------------------------------------
// ROLE QS (kernelA blocks 2048+): q norm-rescale scalars, streaming.
// Dispatched last -> fills the tail as KV/CONV blocks drain.
// ---------------------------------------------------------------------------
static __device__ __forceinline__ void roleQS(
        const float* __restrict__ qkv, const float* __restrict__ scale,
        float* __restrict__ qs_arr, float* rsc_s, int qsb, int t) {
    rsc_s[t] = softplus_rcp(scale[t]);
    __syncthreads();

    const int wave = t >> 6, lane = t & 63;
    const int tk   = lane >> 4;
    const int lr   = lane & 15;
    const int tok0 = qsb * 64;

    float rs[16];
    #pragma unroll
    for (int j = 0; j < 4; j++)
        *(float4*)&rs[j * 4] = *(const float4*)&rsc_s[j * 64 + lr * 4];

    #pragma unroll
    for (int it = 0; it < 4; it++) {
        const int tok = tok0 + it * 16 + wave * 4 + tk;
        const float* src = qkv + (size_t)tok * C_;
        float sq2 = 0.f, sq6 = 0.f;
        #pragma unroll
        for (int j = 0; j < 4; j++) {
            const float4 q4 = *(const float4*)(src + j * 64 + lr * 4);
            const float qa[4] = {q4.x, q4.y, q4.z, q4.w};
            #pragma unroll
            for (int e = 0; e < 4; e++) {
                const float qv = (fmaxf(qa[e], 0.f) + 1e-6f) * rs[j * 4 + e];
                sq2 += qv * qv;
                const float q3 = qv * qv * qv;
                sq6 += q3 * q3;
            }
        }
        #pragma unroll
        for (int m = 1; m < 16; m <<= 1) {
            sq2 += __shfl_xor(sq2, m, 64);
            sq6 += __shfl_xor(sq6, m, 64);
        }
        if (lr == 0) qs_arr[tok] = sqrtf(sq2) * rsqrtf(sq6);
    }
}

// ---------------------------------------------------------------------------
// Kernel A: heterogeneous co-residency. R8 lesson: six structurally
// different kv-kernels all land 50-62us with ALL pipes idle (NB5: VALU 16%,
// HBM 16%, Occ 10%) -- phase-serial structure bubbles every CU in lockstep,
// and hipcc's vmcnt(0)-at-barrier kills intra-block pipelining. Fix: put
// DIFFERENT work on the same CU. Even blocks run KV (latency-bound), odd
// blocks run CONV (VALU-dense, independent of kv), so conv FMAs fill KV's
// memory-stall bubbles. QS blocks (2048+) fill the drain tail. 51.2KB LDS
// union -> 3 blocks/CU mixed-role.
// ---------------------------------------------------------------------------
__global__ __launch_bounds__(256) void kernelA(
        const float* __restrict__ qkv, const float* __restrict__ pos,
        const float* __restrict__ scale,
        const float* __restrict__ w_v,  const float* __restrict__ b_v,
        const float* __restrict__ w_dwc, const float* __restrict__ b_dwc,
        float* __restrict__ out, float* __restrict__ qs_arr,
        float* __restrict__ part, float* __restrict__ kspart) {
    __shared__ float smem[12800];   // conv v_s / KV {kf,v dbuf + rsc} / QS rsc
    const int t   = threadIdx.x;
    const int blk = blockIdx.x;
    if (blk >= 2048) {
        roleQS(qkv, scale, qs_arr, smem, blk - 2048, t);
    } else if (blk & 1) {
        roleCONV(qkv, w_v, b_v, w_dwc, b_dwc, out, smem, blk >> 1, t);
    } else {
        roleKV(qkv, pos, scale, part, kspart, smem, blk >> 1, t);
    }
}

// ---------------------------------------------------------------------------
// Kernel B: reduce 128 per-block partials -> kv_ws[64][1024], ksum_ws[64][32].
// Grid 256 = 64 bh x 4 quarters; partials are L2/L3-resident (just written).
// Writes kv_ws/ksum_ws destructively (no memset needed).
// ---------------------------------------------------------------------------
__global__ __launch_bounds__(256) void kernelB(
        const float* __restrict__ part, const float* __restrict__ kspart,
        float* __restrict__ kv_ws, float* __restrict__ ksum_ws) {
    const int t  = threadIdx.x;
    const int bh = blockIdx.x >> 2, q = blockIdx.x & 3;
    const int b  = bh >> 3, h = bh & 7;

    const float* p = part + (size_t)(b * 128) * 8192 + h * 1024 + q * 256 + t;
    float s = 0.f;
    #pragma unroll 4
    for (int j = 0; j < 128; j++) s += p[(size_t)j * 8192];
    kv_ws[bh * 1024 + q * 256 + t] = s;

    if (q == 0 && t < 32) {
        const float* kp = kspart + (size_t)(b * 128) * 256 + h * 32 + t;
        float s2 = 0.f;
        #pragma unroll 8
        for (int j = 0; j < 128; j++) s2 += kp[(size_t)j * 256];
        ksum_ws[bh * 32 + t] = s2;
    }
}

// ---------------------------------------------------------------------------
// Kernel C: attention epilogue, pure streaming. thread = token; kv (4KB) +
// ks + rsc in LDS (broadcast reads, conflict-free); q 8xfloat4; out RMW
// (conv part written by kernelA; fmaf(o,z,cur) keeps rounding identical to
// the old fused CD2). Tiny LDS + ~90 VGPR -> high occupancy, BW-bound.
// ---------------------------------------------------------------------------
__global__ __launch_bounds__(256) void kernelC(
        const float* __restrict__ qkv, const float* __restrict__ qs_arr,
        const float* __restrict__ kv_ws, const float* __restrict__ ksum_ws,
        const float* __restrict__ scale, float* __restrict__ out) {
    __shared__ float kv_s[1024];
    __shared__ float ks_s[32];
    __shared__ float rsc_s[32];
    const int t    = threadIdx.x;
    const int tile = blockIdx.x & 15;
    const int h    = (blockIdx.x >> 4) & 7;
    const int b    = blockIdx.x >> 7;
    const int bh   = b * NH_ + h;

    ((float4*)kv_s)[t] = ((const float4*)(kv_ws + (size_t)bh * 1024))[t];
    if (t < 32) {
        ks_s[t]  = ksum_ws[bh * HD_ + t];
        rsc_s[t] = softplus_rcp(scale[h * HD_ + t]);
    }
    __syncthreads();

    const int tok = b * N_ + tile * 256 + t;
    float q[32];
    {
        const float4* qsrc = (const float4*)(qkv + (size_t)tok * C_ + h * HD_);
        #pragma unroll
        for (int i = 0; i < 8; i++) ((float4*)q)[i] = qsrc[i];
    }
    const float qs = qs_arr[tok];
    #pragma unroll
    for (int i = 0; i < 32; i++) {
        const float r = (fmaxf(q[i], 0.f) + 1e-6f) * rsc_s[i];
        q[i] = r * r * r * qs;
    }

    float denom = 1e-6f;
    #pragma unroll
    for (int cc = 0; cc < 32; cc++) denom = fmaf(q[cc], ks_s[cc], denom);
    const float z = 1.f / denom;

    float o[32];
    #pragma unroll
    for (int i = 0; i < 32; i++) o[i] = 0.f;
    #pragma unroll
    for (int cc = 0; cc < 32; cc++) {
        const float qc = q[cc];
        #pragma unroll
        for (int d = 0; d < 32; d++)
            o[d] = fmaf(qc, kv_s[cc * 32 + d], o[d]);
    }
    float4* dst = (float4*)(out + (size_t)tok * C_ + h * HD_);
    #pragma unroll
    for (int i = 0; i < 8; i++) {
        float4 cur = dst[i];
        cur.x = fmaf(o[i*4+0], z, cur.x);
        cur.y = fmaf(o[i*4+1], z, cur.y);
        cur.z = fmaf(o[i*4+2], z, cur.z);
        cur.w = fmaf(o[i*4+3], z, cur.w);
        dst[i] = cur;
    }
}

// ---------------------------------------------------------------------------
extern "C" void kernel_launch(void* const* d_in, const int* in_sizes, int n_in,
                              void* d_out, int out_size, void* d_ws, size_t ws_size,
                              hipStream_t stream) {
    const float* qkv   = (const float*)d_in[0];
    const float* pos   = (const float*)d_in[1];
    const float* scale = (const float*)d_in[2];
    const float* w_v   = (const float*)d_in[3];
    const float* b_v   = (const float*)d_in[4];
    const float* w_dwc = (const float*)d_in[5];
    const float* b_dwc = (const float*)d_in[6];
    float* out = (float*)d_out;

    float* qs_arr  = (float*)d_ws;                       // 32768 floats
    float* part    = qs_arr + (size_t)B_ * N_;           // 1024*8192 floats
    float* kspart  = part + (size_t)1024 * 8192;         // 1024*256 floats
    float* kv_ws   = kspart + (size_t)1024 * 256;        // 64*1024 floats
    float* ksum_ws = kv_ws + 64 * 1024;                  // 64*32 floats

    kernelA<<<dim3(2560), 256, 0, stream>>>(qkv, pos, scale, w_v, b_v,
                                            w_dwc, b_dwc, out, qs_arr,
                                            part, kspart);
    kernelB<<<dim3(256), 256, 0, stream>>>(part, kspart, kv_ws, ksum_ws);
    kernelC<<<dim3(1024), 256, 0, stream>>>(qkv, qs_arr, kv_ws, ksum_ws,
                                            scale, out);
}

// Round 10
// 224.417 us; speedup vs baseline: 1.1801x; 1.1801x over previous
//
#include <hip/hip_runtime.h>
#include <math.h>

#define B_  8
#define R_  64
#define C_  256
#define NH_ 8
#define N_  4096
#define HD_ 32
#define LDP 260   // padded LDS row stride (floats)

__device__ __forceinline__ float softplus_rcp(float s) {
    return 1.f / __logf(1.f + __expf(s));     // 1/softplus, fast intrinsics
}

// ---------------------------------------------------------------------------
// Kernel NB4: fused norms + kv aggregation (R4 verbatim -- measured best
// total 223.07). 512 blocks x 64 tokens, 4 tiles of 16 rows, double-buffered
// LDS (67KB -> 2 blocks/CU), register-staged pipeline:
//   LOAD(0); PROC(0); LOAD(1); bar;
//   t: COMP(t) | PROC(t+1) | LOAD(t+2) | bar
// phase 1 (PROC): lane (tk,lr) owns 16 ch of token tk; 4-step 16-lane
//   butterfly for qs/ks; kfin=kw^3*ks -> LDS, v -> LDS.
// phase 2 (COMP): thread (h,cg,dg) accumulates 4x8 sub-tile of head kv;
//   ksum piggybacks on kr reads (dg==0 writes it).
// Epilogue: LDS-staged coalesced partial writes (no atomics; kernelR reduces).
// ---------------------------------------------------------------------------
__global__ __launch_bounds__(256) void kernelNB4(
        const float* __restrict__ qkv, const float* __restrict__ pos,
        const float* __restrict__ scale,
        float* __restrict__ qs_arr, float* __restrict__ part,
        float* __restrict__ kspart) {
    __shared__ float smem[16896];           // 67.6 KB -> 2 blocks/CU
    float* rsc_s = smem + 16640;            // [256]

    const int t    = threadIdx.x;
    const int wave = t >> 6, lane = t & 63;
    const int tk   = lane >> 4;             // token sub-group within wave 0..3
    const int lr   = lane & 15;             // lane within token's 16-lane group
    const int blk  = blockIdx.x;
    const int tok0 = blk * 64;
    const int row  = wave * 4 + tk;         // 0..15: this lane's row in a tile

    rsc_s[t] = softplus_rcp(scale[t]);

    const size_t qbase = (size_t)tok0 * C_;
    const size_t koff  = (size_t)B_ * N_ * C_;
    const size_t voff  = (size_t)2 * B_ * N_ * C_;

    const int h  = t >> 5;                  // head 0..7
    const int l  = t & 31;
    const int cg = l & 7;                   // c sub-tile: cg*4 .. cg*4+3
    const int dg = l >> 3;                  // d sub-tile: dg*8 .. dg*8+7

    float acc[4][8];
    #pragma unroll
    for (int ii = 0; ii < 4; ii++)
        #pragma unroll
        for (int jj = 0; jj < 8; jj++) acc[ii][jj] = 0.f;
    float ksp[4] = {0.f, 0.f, 0.f, 0.f};    // ksum piggyback (dg==0 writes)

    float4 sq[4], sk[4], sv[4], sp[4];      // register staging for one tile

    auto LOAD = [&](int tt) {
        const int    nrow = tt * 16 + row;
        const size_t off  = qbase + (size_t)nrow * C_;
        const size_t poff = (size_t)((tok0 + nrow) & (N_ - 1)) * C_;
        #pragma unroll
        for (int j = 0; j < 4; j++) {
            const int c = j * 64 + lr * 4;
            sq[j] = *(const float4*)(qkv + off + c);
            sk[j] = *(const float4*)(qkv + koff + off + c);
            sv[j] = *(const float4*)(qkv + voff + off + c);
            sp[j] = *(const float4*)(pos + poff + c);
        }
    };

    auto PROC = [&](int tt) {
        float* kf_s = (tt & 1) ? smem + 4160  : smem;
        float* v_s  = (tt & 1) ? smem + 12480 : smem + 8320;
        const int tok = tok0 + tt * 16 + row;
        float kc[16];
        float sq2 = 0.f, sq6 = 0.f, sk2 = 0.f, sk6 = 0.f;
        #pragma unroll
        for (int j = 0; j < 4; j++) {
            const int c = j * 64 + lr * 4;
            *(float4*)&v_s[row * LDP + c] = sv[j];
            const float qa[4] = {sq[j].x, sq[j].y, sq[j].z, sq[j].w};
            const float ka[4] = {sk[j].x, sk[j].y, sk[j].z, sk[j].w};
            const float pa[4] = {sp[j].x, sp[j].y, sp[j].z, sp[j].w};
            #pragma unroll
            for (int e = 0; e < 4; e++) {
                const float r  = rsc_s[c + e];
                const float qv = (fmaxf(qa[e], 0.f) + 1e-6f) * r;
                const float kw = (fmaxf(ka[e] + pa[e], 0.f) + 1e-6f) * r;
                sq2 += qv * qv;  sk2 += kw * kw;
                const float q3 = qv * qv * qv, k3 = kw * kw * kw;
                sq6 += q3 * q3;  sk6 += k3 * k3;
                kc[j * 4 + e] = k3;
            }
        }
        #pragma unroll
        for (int m = 1; m < 16; m <<= 1) {       // 4-step 16-lane butterfly
            sq2 += __shfl_xor(sq2, m, 64);
            sq6 += __shfl_xor(sq6, m, 64);
            sk2 += __shfl_xor(sk2, m, 64);
            sk6 += __shfl_xor(sk6, m, 64);
        }
        if (lr == 0) qs_arr[tok] = sqrtf(sq2) * rsqrtf(sq6);
        const float ks = sqrtf(sk2) * rsqrtf(sk6);
        #pragma unroll
        for (int j = 0; j < 4; j++) {
            const float4 kf4 = make_float4(kc[j*4+0] * ks, kc[j*4+1] * ks,
                                           kc[j*4+2] * ks, kc[j*4+3] * ks);
            *(float4*)&kf_s[row * LDP + j * 64 + lr * 4] = kf4;
        }
    };

    auto COMP = [&](int tt) {
        const float* kf_s = (tt & 1) ? smem + 4160  : smem;
        const float* v_s  = (tt & 1) ? smem + 12480 : smem + 8320;
        const float* kfp = kf_s + h * HD_ + cg * 4;
        const float* vp  = v_s  + h * HD_ + dg * 8;
        #pragma unroll 4
        for (int nl = 0; nl < 16; nl++) {
            const float4 kr = *(const float4*)(kfp + nl * LDP);
            const float4 va = *(const float4*)(vp  + nl * LDP);
            const float4 vb = *(const float4*)(vp  + nl * LDP + 4);
            ksp[0] += kr.x;  ksp[1] += kr.y;
            ksp[2] += kr.z;  ksp[3] += kr.w;
            const float kk[4] = {kr.x, kr.y, kr.z, kr.w};
            const float vv[8] = {va.x, va.y, va.z, va.w,
                                 vb.x, vb.y, vb.z, vb.w};
            #pragma unroll
            for (int ii = 0; ii < 4; ii++)
                #pragma unroll
                for (int jj = 0; jj < 8; jj++)
                    acc[ii][jj] = fmaf(kk[ii], vv[jj], acc[ii][jj]);
        }
    };

    LOAD(0);
    __syncthreads();                 // rsc_s ready (loads already in flight)
    PROC(0);
    LOAD(1);
    __syncthreads();
    #pragma unroll
    for (int tt = 0; tt < 4; tt++) {
        COMP(tt);
        if (tt < 3) PROC(tt + 1);
        if (tt < 2) LOAD(tt + 2);
        if (tt < 3) __syncthreads();
    }
    __syncthreads();                 // COMP(3) done before staging overwrite

    // ---- epilogue: stage kv partial in LDS, write coalesced (no atomics) --
    #pragma unroll
    for (int ii = 0; ii < 4; ii++) {
        const float4 a = make_float4(acc[ii][0], acc[ii][1], acc[ii][2], acc[ii][3]);
        const float4 b = make_float4(acc[ii][4], acc[ii][5], acc[ii][6], acc[ii][7]);
        const int base = h * 1024 + (cg * 4 + ii) * 32 + dg * 8;
        *(float4*)&smem[base]     = a;
        *(float4*)&smem[base + 4] = b;
    }
    if (dg == 0)                              // ksum partial, channel h*32+cg*4
        *(float4*)&kspart[(size_t)blk * 256 + h * 32 + cg * 4] =
            make_float4(ksp[0], ksp[1], ksp[2], ksp[3]);
    __syncthreads();
    float* pdst = part + (size_t)blk * 8192;
    #pragma unroll
    for (int i = 0; i < 8; i++)
        *(float4*)&pdst[i * 1024 + t * 4] = *(const float4*)&smem[i * 1024 + t * 4];
}

// ---------------------------------------------------------------------------
// Kernel R: reduce 64 per-block partials -> kv_ws[64][1024], ksum_ws[64][32].
// Grid 256 = 64 bh x 4 quarters; partials are L2/L3-resident (just written).
// Writes kv_ws/ksum_ws destructively (no memset needed). [R4 verbatim]
// ---------------------------------------------------------------------------
__global__ __launch_bounds__(256) void kernelR(
        const float* __restrict__ part, const float* __restrict__ kspart,
        float* __restrict__ kv_ws, float* __restrict__ ksum_ws) {
    const int t  = threadIdx.x;
    const int bh = blockIdx.x >> 2, q = blockIdx.x & 3;
    const int b  = bh >> 3, h = bh & 7;

    const float* p = part + (size_t)(b * 64) * 8192 + h * 1024 + q * 256 + t;
    float s = 0.f;
    #pragma unroll 4
    for (int j = 0; j < 64; j++) s += p[(size_t)j * 8192];
    kv_ws[bh * 1024 + q * 256 + t] = s;

    if (q == 0 && t < 32) {
        const float* kp = kspart + (size_t)(b * 64) * 256 + h * 32 + t;
        float s2 = 0.f;
        #pragma unroll 8
        for (int j = 0; j < 64; j++) s2 += kp[(size_t)j * 256];
        ksum_ws[bh * 32 + t] = s2;
    }
}

// ---------------------------------------------------------------------------
// Kernel CD5: R4's CD2 with EXACTLY ONE change (A/B vs the 223.07 best):
// q + qs are prefetched into registers at kernel start, issued behind the
// halo loads, so the attn phase doesn't start with a cold ~900cy q-load
// chain after two barriers. Everything else (LDS kv_s staging, conv ring,
// res re-stage at stride 33, single plain-float4 out store) is identical
// to the verified CD2.
// ---------------------------------------------------------------------------
__global__ __launch_bounds__(256) void kernelCD5(
        const float* __restrict__ qkv, const float* __restrict__ qs_arr,
        const float* __restrict__ kv_ws, const float* __restrict__ ksum_ws,
        const float* __restrict__ scale,
        const float* __restrict__ w_v,  const float* __restrict__ b_v,
        const float* __restrict__ w_dwc, const float* __restrict__ b_dwc,
        float* __restrict__ out) {
    __shared__ float v_s[20 * 20 * 32];   // 51.2 KB; reused as conv_s (256*33)
    __shared__ float kv_s[1024];
    __shared__ float ks_s[32];
    __shared__ float rsc_s[32];
    const int t    = threadIdx.x;
    const int tile = blockIdx.x;
    const int h    = blockIdx.y;
    const int b    = blockIdx.z;
    const int ty0  = (tile >> 2) * 16, tx0 = (tile & 3) * 16;
    const int bh   = b * NH_ + h;

    ((float4*)kv_s)[t] = ((const float4*)(kv_ws + (size_t)bh * 1024))[t];
    if (t < 32) {
        ks_s[t]  = ksum_ws[bh * HD_ + t];
        rsc_s[t] = softplus_rcp(scale[h * HD_ + t]);
    }

    const float* vb = qkv + (size_t)2 * B_ * N_ * C_ + (size_t)b * N_ * C_ + h * HD_;
    #pragma unroll
    for (int i = 0; i < 13; i++) {
        const int idx = i * 256 + t;
        if (idx < 3200) {
            const int pix = idx >> 3, d4 = (idx & 7) * 4;
            const int yy = pix / 20, xx = pix - yy * 20;
            const int gy = ty0 + yy - 2, gx = tx0 + xx - 2;
            float4 val = make_float4(0.f, 0.f, 0.f, 0.f);
            if (gy >= 0 && gy < R_ && gx >= 0 && gx < R_)
                val = *(const float4*)(vb + (size_t)(gy * R_ + gx) * C_ + d4);
            *(float4*)&v_s[pix * 32 + d4] = val;
        }
    }

    // ---- THE ONE CHANGE: prefetch q + qs behind the halo loads ----
    const int tyy = t >> 4, txx = t & 15;
    const int tok = b * N_ + (ty0 + tyy) * R_ + (tx0 + txx);
    float qreg[32];
    {
        const float4* qsrc = (const float4*)(qkv + (size_t)tok * C_ + h * HD_);
        #pragma unroll
        for (int i = 0; i < 8; i++) ((float4*)qreg)[i] = qsrc[i];
    }
    const float qs = qs_arr[tok];

    const int c  = t & 31, pg = t >> 5;
    float wv[9], wd[25];
    {
        const float* wvp = w_v + (size_t)(h * HD_ + c) * 9;
        const float* wdp = w_dwc + (size_t)c * 25;
        #pragma unroll
        for (int i = 0; i < 9; i++)  wv[i] = wvp[i];
        #pragma unroll
        for (int i = 0; i < 25; i++) wd[i] = wdp[i];
    }
    const float bias = b_v[h * HD_ + c] + b_dwc[c];
    __syncthreads();

    // ---- conv phase: thread = (channel c, 2 tile rows), ring window ----
    float res[32];
    #pragma unroll
    for (int r2 = 0; r2 < 2; r2++) {
        const int ty = pg * 2 + r2;
        float win[5][5];
        #pragma unroll
        for (int j = 0; j < 5; j++)
            #pragma unroll
            for (int i = 0; i < 5; i++)
                win[j][i] = v_s[((ty + i) * 20 + j) * 32 + c];
        #pragma unroll
        for (int tx = 0; tx < 16; tx++) {
            float a = bias;
            #pragma unroll
            for (int j = 0; j < 5; j++) {
                const int slot = (tx + j) % 5;
                #pragma unroll
                for (int i = 0; i < 5; i++)
                    a = fmaf(wd[i * 5 + j], win[slot][i], a);
            }
            #pragma unroll
            for (int j = 1; j < 4; j++) {
                const int slot = (tx + j) % 5;
                #pragma unroll
                for (int i = 1; i < 4; i++)
                    a = fmaf(wv[(i - 1) * 3 + (j - 1)], win[slot][i], a);
            }
            res[r2 * 16 + tx] = a;
            if (tx < 15) {
                const int slot = tx % 5;
                #pragma unroll
                for (int i = 0; i < 5; i++)
                    win[slot][i] = v_s[((ty + i) * 20 + (tx + 5)) * 32 + c];
            }
        }
    }
    __syncthreads();
    #pragma unroll
    for (int r2 = 0; r2 < 2; r2++)
        #pragma unroll
        for (int tx = 0; tx < 16; tx++)
            v_s[((pg * 2 + r2) * 16 + tx) * 33 + c] = res[r2 * 16 + tx];
    __syncthreads();

    // ---- attention phase: thread = pixel; q already in registers ----
    {
        #pragma unroll
        for (int i = 0; i < 32; i++) {
            const float r = (fmaxf(qreg[i], 0.f) + 1e-6f) * rsc_s[i];
            qreg[i] = r * r * r * qs;
        }

        float denom = 1e-6f;
        #pragma unroll
        for (int cc = 0; cc < 32; cc++) denom = fmaf(qreg[cc], ks_s[cc], denom);
        const float z = 1.f / denom;

        float o[32];
        #pragma unroll
        for (int i = 0; i < 32; i++) o[i] = 0.f;
        #pragma unroll
        for (int cc = 0; cc < 32; cc++) {
            const float qc = qreg[cc];
            #pragma unroll
            for (int d = 0; d < 32; d++)
                o[d] = fmaf(qc, kv_s[cc * 32 + d], o[d]);
        }
        float4* dst = (float4*)(out + (size_t)tok * C_ + h * HD_);
        #pragma unroll
        for (int i = 0; i < 8; i++) {
            float4 v4;
            v4.x = fmaf(o[i*4+0], z, v_s[t * 33 + i*4+0]);
            v4.y = fmaf(o[i*4+1], z, v_s[t * 33 + i*4+1]);
            v4.z = fmaf(o[i*4+2], z, v_s[t * 33 + i*4+2]);
            v4.w = fmaf(o[i*4+3], z, v_s[t * 33 + i*4+3]);
            dst[i] = v4;
        }
    }
}

// ---------------------------------------------------------------------------
extern "C" void kernel_launch(void* const* d_in, const int* in_sizes, int n_in,
                              void* d_out, int out_size, void* d_ws, size_t ws_size,
                              hipStream_t stream) {
    const float* qkv   = (const float*)d_in[0];
    const float* pos   = (const float*)d_in[1];
    const float* scale = (const float*)d_in[2];
    const float* w_v   = (const float*)d_in[3];
    const float* b_v   = (const float*)d_in[4];
    const float* w_dwc = (const float*)d_in[5];
    const float* b_dwc = (const float*)d_in[6];
    float* out = (float*)d_out;

    float* qs_arr  = (float*)d_ws;                       // 32768 floats
    float* part    = qs_arr + (size_t)B_ * N_;           // 512*8192 floats
    float* kspart  = part + (size_t)512 * 8192;          // 512*256 floats
    float* kv_ws   = kspart + (size_t)512 * 256;         // 64*1024 floats
    float* ksum_ws = kv_ws + 64 * 1024;                  // 64*32 floats

    kernelNB4<<<dim3(512), 256, 0, stream>>>(qkv, pos, scale, qs_arr, part, kspart);
    kernelR<<<dim3(256), 256, 0, stream>>>(part, kspart, kv_ws, ksum_ws);
    kernelCD5<<<dim3(16, NH_, B_), 256, 0, stream>>>(qkv, qs_arr, kv_ws, ksum_ws,
                                                     scale, w_v, b_v, w_dwc, b_dwc, out);
}